// Round 3
// baseline (466.587 us; speedup 1.0000x reference)
//
#include <hip/hip_runtime.h>
#include <stdint.h>

// Problem constants
#define S_LEN   2048
#define D_MODEL 1024
#define N_HEADS 16
#define HEAD_D  64
#define BATCH   2
#define M_TOT   (BATCH * S_LEN)   // 4096 rows for the QKV projection GEMM

typedef __attribute__((ext_vector_type(8))) short s8v;            // 8 x bf16 (MFMA A/B frag)
typedef __attribute__((ext_vector_type(4))) float f4v;            // 4 x f32  (MFMA C/D frag)
typedef __attribute__((ext_vector_type(4))) unsigned short u4v;   // 4 x bf16 packed store

__device__ __forceinline__ float bf2f(unsigned short u) {
    union { unsigned int i; float f; } c; c.i = ((unsigned int)u) << 16; return c.f;
}
__device__ __forceinline__ unsigned short f2bf(float f) {
    union { float f; unsigned int i; } c; c.f = f;
    unsigned int u = c.i + 0x7FFFu + ((c.i >> 16) & 1u);   // round-nearest-even
    return (unsigned short)(u >> 16);
}
__device__ __forceinline__ unsigned int pk2bf(float lo, float hi) {
    return (unsigned int)f2bf(lo) | ((unsigned int)f2bf(hi) << 16);
}
// exp2 via the HW transcendental (v_exp_f32)
__device__ __forceinline__ float hw_exp2(float x) { return __builtin_amdgcn_exp2f(x); }

// async global->LDS, 16B per lane; LDS dest must be wave-uniform base (+lane*16 implicit)
#define GLD16(gp, lp) __builtin_amdgcn_global_load_lds(                      \
    (const __attribute__((address_space(1))) void*)(const void*)(gp),        \
    (__attribute__((address_space(3))) void*)(void*)(lp), 16, 0, 0)

// exp(x*0.125) == exp2(x * 0.125*log2(e))
#define EXP_SCALE 0.1803368801111204f

// ---------------- kernel 0: fp32 -> bf16 conversion ----------------
__global__ __launch_bounds__(256) void cvt_bf16(const float* __restrict__ src,
                                                unsigned short* __restrict__ dst, int n) {
    int i = (blockIdx.x * 256 + threadIdx.x) * 4;
    int stride = gridDim.x * 1024;
    for (; i < n; i += stride) {
        float4 v = *(const float4*)(src + i);
        u4v o;
        o[0] = f2bf(v.x); o[1] = f2bf(v.y); o[2] = f2bf(v.z); o[3] = f2bf(v.w);
        *(u4v*)(dst + i) = o;
    }
}

// ---------------- kernel 1: QKV projection GEMM (m97 structure) ----------------
// C[m][e] = sum_k X[m][k] * W[e][k] + b[e]
// z=0 -> Q[b,h,s,dh], z=1 -> K[b,h,s,dh], z=2 -> V^T[b,h,dh,s]
__global__ __launch_bounds__(256) void qkv_gemm(
    const unsigned short* __restrict__ X,
    const unsigned short* __restrict__ Wq, const unsigned short* __restrict__ Wk,
    const unsigned short* __restrict__ Wv,
    const float* __restrict__ bq, const float* __restrict__ bk, const float* __restrict__ bv,
    unsigned short* __restrict__ q_ws, unsigned short* __restrict__ k_ws,
    unsigned short* __restrict__ vt_ws) {
    __shared__ unsigned short sA[128 * 32];
    __shared__ unsigned short sB[128 * 32];

    const int z = blockIdx.z;
    const unsigned short* Wm = (z == 0) ? Wq : ((z == 1) ? Wk : Wv);
    const float* bm = (z == 0) ? bq : ((z == 1) ? bk : bv);
    const int m0 = blockIdx.x * 128, n0 = blockIdx.y * 128;
    const int t = threadIdx.x;
    const int lane = t & 63, w = t >> 6;
    const int fr = lane & 15, g = lane >> 4;
    const int wr = w >> 1, wc = w & 1;

    f4v acc[4][4];
#pragma unroll
    for (int i = 0; i < 4; ++i)
#pragma unroll
        for (int j = 0; j < 4; ++j) acc[i][j] = (f4v){0.f, 0.f, 0.f, 0.f};

    const int rowL = t >> 2;
    const int colL = (t & 3) * 8;
    const unsigned short* gA = X + (size_t)(m0 + rowL) * D_MODEL + colL;
    const unsigned short* gB = Wm + (size_t)(n0 + rowL) * D_MODEL + colL;

    for (int kb = 0; kb < 32; ++kb) {
        const int k0 = kb * 32;
        GLD16(gA + k0,                 sA + w * 512);
        GLD16(gA + 64 * D_MODEL + k0,  sA + 2048 + w * 512);
        GLD16(gB + k0,                 sB + w * 512);
        GLD16(gB + 64 * D_MODEL + k0,  sB + 2048 + w * 512);
        __syncthreads();

        s8v af[4], bfv[4];
#pragma unroll
        for (int i = 0; i < 4; ++i)
            af[i] = *(const s8v*)(sA + (wr * 64 + i * 16 + fr) * 32 + g * 8);
#pragma unroll
        for (int j = 0; j < 4; ++j)
            bfv[j] = *(const s8v*)(sB + (wc * 64 + j * 16 + fr) * 32 + g * 8);
#pragma unroll
        for (int i = 0; i < 4; ++i)
#pragma unroll
            for (int j = 0; j < 4; ++j)
                acc[i][j] = __builtin_amdgcn_mfma_f32_16x16x32_bf16(af[i], bfv[j], acc[i][j], 0, 0, 0);
        __syncthreads();
    }

    const int e_base = n0 + wc * 64;
    const int m_base = m0 + wr * 64;
    if (z < 2) {
        unsigned short* dst = (z == 0) ? q_ws : k_ws;
#pragma unroll
        for (int i = 0; i < 4; ++i) {
#pragma unroll
            for (int j = 0; j < 4; ++j) {
                const int e = e_base + j * 16 + fr;
                const int h = e >> 6, dh = e & 63;
                const float bias = bm[e];
                const int mr = m_base + i * 16 + g * 4;
                const int b_ = mr >> 11, srow = mr & 2047;
                const size_t base = (((size_t)(b_ * N_HEADS + h) * S_LEN + srow) << 6) + dh;
#pragma unroll
                for (int r = 0; r < 4; ++r)
                    dst[base + ((size_t)r << 6)] = f2bf(acc[i][j][r] + bias);
            }
        }
    } else {
#pragma unroll
        for (int i = 0; i < 4; ++i) {
#pragma unroll
            for (int j = 0; j < 4; ++j) {
                const int e = e_base + j * 16 + fr;
                const int h = e >> 6, dh = e & 63;
                const float bias = bm[e];
                const int mr = m_base + i * 16 + g * 4;
                const int b_ = mr >> 11, srow = mr & 2047;
                u4v pk;
#pragma unroll
                for (int r = 0; r < 4; ++r) pk[r] = f2bf(acc[i][j][r] + bias);
                *(u4v*)(vt_ws + ((size_t)(b_ * N_HEADS + h) * HEAD_D + dh) * S_LEN + srow) = pk;
            }
        }
    }
}

// ---------------- kernel 2: fused attention, wave-per-q-tile ----------------
// One wave (64 lanes) owns one (bh, 16-row q-tile); 4 independent waves per WG,
// NO __syncthreads. Swapped QK^T (mfma(K,Q) -> S[key][q=fr]) makes q lane-local:
// rowsum reduce = 2 shfl_xor; normalization is one per-lane scalar.
// Phase A computes rowsums (exp recompute is cheap: MfmaUtil was 4%).
// Phase B recomputes scores, stores fp32 normalized weights straight from
// registers (coalesced, spread over the whole kernel), packs P to bf16, and
// exchanges through a 1KB XOR-swizzled LDS tile into the PV A-frag layout.
__global__ __launch_bounds__(256) void attn_fused2(
    const unsigned short* __restrict__ q_ws, const unsigned short* __restrict__ k_ws,
    const unsigned short* __restrict__ vt_ws,
    float* __restrict__ out, float* __restrict__ wts) {
    __shared__ unsigned short Pex[4 * 512];   // 4 waves x 1KB

    const int t = threadIdx.x, lane = t & 63, w = t >> 6;
    const int fr = lane & 15, g = lane >> 4;
    const int blk = blockIdx.x;
    const int bh = blk >> 5;                 // 32 blocks per (b,h)
    const int qt = (blk & 31) * 4 + w;       // q-tile 0..127

    const unsigned short* Qp = q_ws + ((size_t)bh * S_LEN + qt * 16) * HEAD_D;
    const unsigned short* Kp = k_ws + (size_t)bh * S_LEN * HEAD_D;
    const unsigned short* Vt = vt_ws + (size_t)bh * HEAD_D * S_LEN;
    float* wbase = wts + ((size_t)bh * S_LEN + (size_t)qt * 16) * S_LEN;

    // Q fragment: lane(fr,g) holds Q[q=fr][dh = g*8..+7] (and +32) — serves as
    // the B-frag of the swapped QK^T directly.
    const s8v qa0 = *(const s8v*)(Qp + fr * HEAD_D + g * 8);
    const s8v qa1 = *(const s8v*)(Qp + fr * HEAD_D + 32 + g * 8);

    // ---- phase A: rowsums ----
    float rsum = 0.f;
    for (int c = 0; c < 64; ++c) {
        const unsigned short* kc = Kp + (size_t)(c * 32 + fr) * HEAD_D + g * 8;
        const s8v ka0 = *(const s8v*)(kc);
        const s8v ka1 = *(const s8v*)(kc + 32);
        const s8v kb0 = *(const s8v*)(kc + 16 * HEAD_D);
        const s8v kb1 = *(const s8v*)(kc + 16 * HEAD_D + 32);
        f4v sA = (f4v){0.f, 0.f, 0.f, 0.f}, sB = (f4v){0.f, 0.f, 0.f, 0.f};
        sA = __builtin_amdgcn_mfma_f32_16x16x32_bf16(ka0, qa0, sA, 0, 0, 0);
        sA = __builtin_amdgcn_mfma_f32_16x16x32_bf16(ka1, qa1, sA, 0, 0, 0);
        sB = __builtin_amdgcn_mfma_f32_16x16x32_bf16(kb0, qa0, sB, 0, 0, 0);
        sB = __builtin_amdgcn_mfma_f32_16x16x32_bf16(kb1, qa1, sB, 0, 0, 0);
#pragma unroll
        for (int r = 0; r < 4; ++r)
            rsum += hw_exp2(sA[r] * EXP_SCALE) + hw_exp2(sB[r] * EXP_SCALE);
    }
    rsum += __shfl_xor(rsum, 16);
    rsum += __shfl_xor(rsum, 32);
    const float inv = 1.f / rsum;            // per-lane: inv rowsum of q-row fr

    // ---- phase B: weights out + PV ----
    f4v acc[4];
#pragma unroll
    for (int i = 0; i < 4; ++i) acc[i] = (f4v){0.f, 0.f, 0.f, 0.f};
    char* lds = (char*)(Pex + w * 512);
    const int sw = (fr & 3) << 4;            // XOR swizzle (16B granular)

    for (int c = 0; c < 64; ++c) {
        const unsigned short* kc = Kp + (size_t)(c * 32 + fr) * HEAD_D + g * 8;
        const s8v ka0 = *(const s8v*)(kc);
        const s8v ka1 = *(const s8v*)(kc + 32);
        const s8v kb0 = *(const s8v*)(kc + 16 * HEAD_D);
        const s8v kb1 = *(const s8v*)(kc + 16 * HEAD_D + 32);
        f4v sA = (f4v){0.f, 0.f, 0.f, 0.f}, sB = (f4v){0.f, 0.f, 0.f, 0.f};
        sA = __builtin_amdgcn_mfma_f32_16x16x32_bf16(ka0, qa0, sA, 0, 0, 0);
        sA = __builtin_amdgcn_mfma_f32_16x16x32_bf16(ka1, qa1, sA, 0, 0, 0);
        sB = __builtin_amdgcn_mfma_f32_16x16x32_bf16(kb0, qa0, sB, 0, 0, 0);
        sB = __builtin_amdgcn_mfma_f32_16x16x32_bf16(kb1, qa1, sB, 0, 0, 0);

        // normalized P in f32; lane(fr,g) reg r = P[key = c*32 + tile*16 + g*4+r][q=fr]
        f4v pA, pB;
#pragma unroll
        for (int r = 0; r < 4; ++r) {
            pA[r] = hw_exp2(sA[r] * EXP_SCALE) * inv;
            pB[r] = hw_exp2(sB[r] * EXP_SCALE) * inv;
        }

        // fp32 weights straight to HBM: W[q=fr][c*32 + tile*16 + g*4 .. +3]
        float* wrow = wbase + (size_t)fr * S_LEN + c * 32 + g * 4;
        *(f4v*)(wrow)      = pA;
        *(f4v*)(wrow + 16) = pB;

        // pack to bf16 and exchange via LDS into PV A-frag layout
        const unsigned int d0A = pk2bf(pA[0], pA[1]), d1A = pk2bf(pA[2], pA[3]);
        const unsigned int d0B = pk2bf(pB[0], pB[1]), d1B = pk2bf(pB[2], pB[3]);
        const int wb = fr * 64 + g * 8;          // [q=fr][key], 2B/key, 64B/row
        *(unsigned int*)(lds + ((wb)      ^ sw))      = d0A;
        *(unsigned int*)(lds + ((wb + 4)  ^ sw))      = d1A;
        *(unsigned int*)(lds + ((wb + 32) ^ sw))      = d0B;
        *(unsigned int*)(lds + ((wb + 36) ^ sw))      = d1B;
        const s8v pa = *(const s8v*)(lds + ((fr * 64 + g * 16) ^ sw));

#pragma unroll
        for (int tt = 0; tt < 4; ++tt) {
            const s8v vb = *(const s8v*)(Vt + (size_t)(tt * 16 + fr) * S_LEN + c * 32 + g * 8);
            acc[tt] = __builtin_amdgcn_mfma_f32_16x16x32_bf16(pa, vb, acc[tt], 0, 0, 0);
        }
    }

    // ---- epilogue: O (already normalized) ----
    const int b_ = bh >> 4, h = bh & 15;
#pragma unroll
    for (int tt = 0; tt < 4; ++tt) {
#pragma unroll
        for (int r = 0; r < 4; ++r) {
            out[((size_t)b_ * S_LEN + qt * 16 + g * 4 + r) * D_MODEL + h * HEAD_D + tt * 16 + fr] =
                acc[tt][r];
        }
    }
}

// ---------------- launch ----------------
extern "C" void kernel_launch(void* const* d_in, const int* in_sizes, int n_in,
                              void* d_out, int out_size, void* d_ws, size_t ws_size,
                              hipStream_t stream) {
    const float* x  = (const float*)d_in[0];
    const float* Wq = (const float*)d_in[1];
    const float* bq = (const float*)d_in[2];
    const float* Wk = (const float*)d_in[3];
    const float* bk = (const float*)d_in[4];
    const float* Wv = (const float*)d_in[5];
    const float* bv = (const float*)d_in[6];

    float* out = (float*)d_out;                              // [2,2048,1024]
    float* wts = out + (size_t)BATCH * S_LEN * D_MODEL;      // [2,16,2048,2048]

    unsigned short* xb    = (unsigned short*)d_ws;
    unsigned short* wqb   = xb  + (size_t)M_TOT * D_MODEL;
    unsigned short* wkb   = wqb + (size_t)D_MODEL * D_MODEL;
    unsigned short* wvb   = wkb + (size_t)D_MODEL * D_MODEL;
    unsigned short* q_ws  = wvb + (size_t)D_MODEL * D_MODEL;             // [b,h,s,dh]
    unsigned short* k_ws  = q_ws + (size_t)M_TOT * D_MODEL;              // [b,h,s,dh]
    unsigned short* vt_ws = k_ws + (size_t)M_TOT * D_MODEL;              // [b,h,dh,s]

    cvt_bf16<<<1024, 256, 0, stream>>>(x,  xb,  M_TOT * D_MODEL);
    cvt_bf16<<<256,  256, 0, stream>>>(Wq, wqb, D_MODEL * D_MODEL);
    cvt_bf16<<<256,  256, 0, stream>>>(Wk, wkb, D_MODEL * D_MODEL);
    cvt_bf16<<<256,  256, 0, stream>>>(Wv, wvb, D_MODEL * D_MODEL);

    qkv_gemm<<<dim3(32, 8, 3), 256, 0, stream>>>(xb, wqb, wkb, wvb, bq, bk, bv,
                                                 q_ws, k_ws, vt_ws);

    attn_fused2<<<BATCH * N_HEADS * (S_LEN / 64), 256, 0, stream>>>(q_ws, k_ws, vt_ws, out, wts);
}

// Round 4
// 441.903 us; speedup vs baseline: 1.0559x; 1.0559x over previous
//
#include <hip/hip_runtime.h>
#include <stdint.h>

// Problem constants
#define S_LEN   2048
#define D_MODEL 1024
#define N_HEADS 16
#define HEAD_D  64
#define BATCH   2
#define M_TOT   (BATCH * S_LEN)   // 4096 rows for the QKV projection GEMM

typedef __attribute__((ext_vector_type(8))) short s8v;            // 8 x bf16 (MFMA A/B frag)
typedef __attribute__((ext_vector_type(4))) float f4v;            // 4 x f32  (MFMA C/D frag)
typedef __attribute__((ext_vector_type(4))) unsigned short u4v;   // 4 x bf16 packed store

__device__ __forceinline__ float bf2f(unsigned short u) {
    union { unsigned int i; float f; } c; c.i = ((unsigned int)u) << 16; return c.f;
}
__device__ __forceinline__ unsigned short f2bf(float f) {
    union { float f; unsigned int i; } c; c.f = f;
    unsigned int u = c.i + 0x7FFFu + ((c.i >> 16) & 1u);   // round-nearest-even
    return (unsigned short)(u >> 16);
}
__device__ __forceinline__ unsigned int pk2bf(float lo, float hi) {
    return (unsigned int)f2bf(lo) | ((unsigned int)f2bf(hi) << 16);
}
// exp2 via the HW transcendental (v_exp_f32)
__device__ __forceinline__ float hw_exp2(float x) { return __builtin_amdgcn_exp2f(x); }

// async global->LDS, 16B per lane; LDS dest must be wave-uniform base (+lane*16 implicit)
#define GLD16(gp, lp) __builtin_amdgcn_global_load_lds(                      \
    (const __attribute__((address_space(1))) void*)(const void*)(gp),        \
    (__attribute__((address_space(3))) void*)(void*)(lp), 16, 0, 0)

// exp(x*0.125) == exp2(x * 0.125*log2(e))
#define EXP_SCALE 0.1803368801111204f

// ---------------- kernel 0: fp32 -> bf16 conversion ----------------
__global__ __launch_bounds__(256) void cvt_bf16(const float* __restrict__ src,
                                                unsigned short* __restrict__ dst, int n) {
    int i = (blockIdx.x * 256 + threadIdx.x) * 4;
    int stride = gridDim.x * 1024;
    for (; i < n; i += stride) {
        float4 v = *(const float4*)(src + i);
        u4v o;
        o[0] = f2bf(v.x); o[1] = f2bf(v.y); o[2] = f2bf(v.z); o[3] = f2bf(v.w);
        *(u4v*)(dst + i) = o;
    }
}

// ---------------- kernel 1: QKV projection GEMM (m97 structure) ----------------
// C[m][e] = sum_k X[m][k] * W[e][k] + b[e]
// z=0 -> Q[b,h,s,dh], z=1 -> K[b,h,s,dh], z=2 -> V^T[b,h,dh,s]
__global__ __launch_bounds__(256) void qkv_gemm(
    const unsigned short* __restrict__ X,
    const unsigned short* __restrict__ Wq, const unsigned short* __restrict__ Wk,
    const unsigned short* __restrict__ Wv,
    const float* __restrict__ bq, const float* __restrict__ bk, const float* __restrict__ bv,
    unsigned short* __restrict__ q_ws, unsigned short* __restrict__ k_ws,
    unsigned short* __restrict__ vt_ws) {
    __shared__ unsigned short sA[128 * 32];
    __shared__ unsigned short sB[128 * 32];

    const int z = blockIdx.z;
    const unsigned short* Wm = (z == 0) ? Wq : ((z == 1) ? Wk : Wv);
    const float* bm = (z == 0) ? bq : ((z == 1) ? bk : bv);
    const int m0 = blockIdx.x * 128, n0 = blockIdx.y * 128;
    const int t = threadIdx.x;
    const int lane = t & 63, w = t >> 6;
    const int fr = lane & 15, g = lane >> 4;
    const int wr = w >> 1, wc = w & 1;

    f4v acc[4][4];
#pragma unroll
    for (int i = 0; i < 4; ++i)
#pragma unroll
        for (int j = 0; j < 4; ++j) acc[i][j] = (f4v){0.f, 0.f, 0.f, 0.f};

    const int rowL = t >> 2;
    const int colL = (t & 3) * 8;
    const unsigned short* gA = X + (size_t)(m0 + rowL) * D_MODEL + colL;
    const unsigned short* gB = Wm + (size_t)(n0 + rowL) * D_MODEL + colL;

    for (int kb = 0; kb < 32; ++kb) {
        const int k0 = kb * 32;
        GLD16(gA + k0,                 sA + w * 512);
        GLD16(gA + 64 * D_MODEL + k0,  sA + 2048 + w * 512);
        GLD16(gB + k0,                 sB + w * 512);
        GLD16(gB + 64 * D_MODEL + k0,  sB + 2048 + w * 512);
        __syncthreads();

        s8v af[4], bfv[4];
#pragma unroll
        for (int i = 0; i < 4; ++i)
            af[i] = *(const s8v*)(sA + (wr * 64 + i * 16 + fr) * 32 + g * 8);
#pragma unroll
        for (int j = 0; j < 4; ++j)
            bfv[j] = *(const s8v*)(sB + (wc * 64 + j * 16 + fr) * 32 + g * 8);
#pragma unroll
        for (int i = 0; i < 4; ++i)
#pragma unroll
            for (int j = 0; j < 4; ++j)
                acc[i][j] = __builtin_amdgcn_mfma_f32_16x16x32_bf16(af[i], bfv[j], acc[i][j], 0, 0, 0);
        __syncthreads();
    }

    const int e_base = n0 + wc * 64;
    const int m_base = m0 + wr * 64;
    if (z < 2) {
        unsigned short* dst = (z == 0) ? q_ws : k_ws;
#pragma unroll
        for (int i = 0; i < 4; ++i) {
#pragma unroll
            for (int j = 0; j < 4; ++j) {
                const int e = e_base + j * 16 + fr;
                const int h = e >> 6, dh = e & 63;
                const float bias = bm[e];
                const int mr = m_base + i * 16 + g * 4;
                const int b_ = mr >> 11, srow = mr & 2047;
                const size_t base = (((size_t)(b_ * N_HEADS + h) * S_LEN + srow) << 6) + dh;
#pragma unroll
                for (int r = 0; r < 4; ++r)
                    dst[base + ((size_t)r << 6)] = f2bf(acc[i][j][r] + bias);
            }
        }
    } else {
#pragma unroll
        for (int i = 0; i < 4; ++i) {
#pragma unroll
            for (int j = 0; j < 4; ++j) {
                const int e = e_base + j * 16 + fr;
                const int h = e >> 6, dh = e & 63;
                const float bias = bm[e];
                const int mr = m_base + i * 16 + g * 4;
                const int b_ = mr >> 11, srow = mr & 2047;
                u4v pk;
#pragma unroll
                for (int r = 0; r < 4; ++r) pk[r] = f2bf(acc[i][j][r] + bias);
                *(u4v*)(vt_ws + ((size_t)(b_ * N_HEADS + h) * HEAD_D + dh) * S_LEN + srow) = pk;
            }
        }
    }
}

// ---------------- kernel 2: fused attention, key-split across waves ----------------
// WG (4 waves) = one (bh, 16-row q-tile). Wave w owns keys [w*512, w*512+512):
// 16 iterations per phase (was 64). Grid = 4096 WGs = 16384 waves (2x device
// wave slots) -> occupancy capped only by LDS/VGPR (~87%).
// Swapped QK^T (mfma(K,Q) -> S[key][q=fr]) keeps q lane-local: rowsum reduce is
// 2 shfl_xor + a 4x16-float LDS combine across waves.
// Phase B recomputes scores (MFMA is ~free at 5% util), writes normalized fp32
// weights straight from registers, exchanges bf16 P through a 1KB/wave LDS tile
// into PV A-frag layout, accumulates partial O; 4-wave O-combine via 16KB LDS.
__global__ __launch_bounds__(256) void attn_fused3(
    const unsigned short* __restrict__ q_ws, const unsigned short* __restrict__ k_ws,
    const unsigned short* __restrict__ vt_ws,
    float* __restrict__ out, float* __restrict__ wts) {
    __shared__ unsigned short Pex[4 * 512];   // 4 KB: per-wave P exchange
    __shared__ float Ocmb[4 * 64 * 16];       // 16 KB: partial-O combine
    __shared__ float rs_lds[4][16];

    const int t = threadIdx.x, lane = t & 63, w = t >> 6;
    const int fr = lane & 15, g = lane >> 4;
    const int blk = blockIdx.x;
    const int bh = blk >> 7;                 // 128 blocks per (b,h)
    const int qt = blk & 127;                // q-tile 0..127

    const unsigned short* Qp = q_ws + ((size_t)bh * S_LEN + qt * 16) * HEAD_D;
    const unsigned short* Kp = k_ws + ((size_t)bh * S_LEN + w * 512) * HEAD_D;
    const unsigned short* Vt = vt_ws + (size_t)bh * HEAD_D * S_LEN;
    float* wbase = wts + ((size_t)bh * S_LEN + (size_t)qt * 16) * S_LEN + w * 512;

    // Q fragment: lane(fr,g) holds Q[q=fr][dh = g*8..+7] (and +32) — the B-frag
    // of the swapped QK^T directly.
    const s8v qa0 = *(const s8v*)(Qp + fr * HEAD_D + g * 8);
    const s8v qa1 = *(const s8v*)(Qp + fr * HEAD_D + 32 + g * 8);

    // ---- phase A: partial rowsums over this wave's 512 keys ----
    float rsum = 0.f;
    for (int c = 0; c < 16; ++c) {
        const unsigned short* kc = Kp + (size_t)(c * 32 + fr) * HEAD_D + g * 8;
        const s8v ka0 = *(const s8v*)(kc);
        const s8v ka1 = *(const s8v*)(kc + 32);
        const s8v kb0 = *(const s8v*)(kc + 16 * HEAD_D);
        const s8v kb1 = *(const s8v*)(kc + 16 * HEAD_D + 32);
        f4v sA = (f4v){0.f, 0.f, 0.f, 0.f}, sB = (f4v){0.f, 0.f, 0.f, 0.f};
        sA = __builtin_amdgcn_mfma_f32_16x16x32_bf16(ka0, qa0, sA, 0, 0, 0);
        sA = __builtin_amdgcn_mfma_f32_16x16x32_bf16(ka1, qa1, sA, 0, 0, 0);
        sB = __builtin_amdgcn_mfma_f32_16x16x32_bf16(kb0, qa0, sB, 0, 0, 0);
        sB = __builtin_amdgcn_mfma_f32_16x16x32_bf16(kb1, qa1, sB, 0, 0, 0);
#pragma unroll
        for (int r = 0; r < 4; ++r)
            rsum += hw_exp2(sA[r] * EXP_SCALE) + hw_exp2(sB[r] * EXP_SCALE);
    }
    rsum += __shfl_xor(rsum, 16);
    rsum += __shfl_xor(rsum, 32);
    if (lane < 16) rs_lds[w][lane] = rsum;   // partial rowsum of q-row `lane`
    __syncthreads();
    const float inv = 1.f / (rs_lds[0][fr] + rs_lds[1][fr] + rs_lds[2][fr] + rs_lds[3][fr]);

    // ---- phase B: weights out + partial PV over this wave's keys ----
    f4v acc[4];
#pragma unroll
    for (int i = 0; i < 4; ++i) acc[i] = (f4v){0.f, 0.f, 0.f, 0.f};
    char* lds = (char*)(Pex + w * 512);
    const int sw = (fr & 3) << 4;            // XOR swizzle (16B granular)

    for (int c = 0; c < 16; ++c) {
        const unsigned short* kc = Kp + (size_t)(c * 32 + fr) * HEAD_D + g * 8;
        const s8v ka0 = *(const s8v*)(kc);
        const s8v ka1 = *(const s8v*)(kc + 32);
        const s8v kb0 = *(const s8v*)(kc + 16 * HEAD_D);
        const s8v kb1 = *(const s8v*)(kc + 16 * HEAD_D + 32);
        f4v sA = (f4v){0.f, 0.f, 0.f, 0.f}, sB = (f4v){0.f, 0.f, 0.f, 0.f};
        sA = __builtin_amdgcn_mfma_f32_16x16x32_bf16(ka0, qa0, sA, 0, 0, 0);
        sA = __builtin_amdgcn_mfma_f32_16x16x32_bf16(ka1, qa1, sA, 0, 0, 0);
        sB = __builtin_amdgcn_mfma_f32_16x16x32_bf16(kb0, qa0, sB, 0, 0, 0);
        sB = __builtin_amdgcn_mfma_f32_16x16x32_bf16(kb1, qa1, sB, 0, 0, 0);

        // normalized P in f32; lane(fr,g) reg r = P[key = w*512 + c*32 + tile*16 + g*4+r][q=fr]
        f4v pA, pB;
#pragma unroll
        for (int r = 0; r < 4; ++r) {
            pA[r] = hw_exp2(sA[r] * EXP_SCALE) * inv;
            pB[r] = hw_exp2(sB[r] * EXP_SCALE) * inv;
        }

        // fp32 weights straight to HBM: W[q=fr][w*512 + c*32 + tile*16 + g*4 .. +3]
        float* wrow = wbase + (size_t)fr * S_LEN + c * 32 + g * 4;
        *(f4v*)(wrow)      = pA;
        *(f4v*)(wrow + 16) = pB;

        // pack to bf16 and exchange via LDS into PV A-frag layout
        const unsigned int d0A = pk2bf(pA[0], pA[1]), d1A = pk2bf(pA[2], pA[3]);
        const unsigned int d0B = pk2bf(pB[0], pB[1]), d1B = pk2bf(pB[2], pB[3]);
        const int wb = fr * 64 + g * 8;          // [q=fr][key], 2B/key, 64B/row
        *(unsigned int*)(lds + ((wb)      ^ sw))      = d0A;
        *(unsigned int*)(lds + ((wb + 4)  ^ sw))      = d1A;
        *(unsigned int*)(lds + ((wb + 32) ^ sw))      = d0B;
        *(unsigned int*)(lds + ((wb + 36) ^ sw))      = d1B;
        const s8v pa = *(const s8v*)(lds + ((fr * 64 + g * 16) ^ sw));

#pragma unroll
        for (int tt = 0; tt < 4; ++tt) {
            const s8v vb = *(const s8v*)(Vt + (size_t)(tt * 16 + fr) * S_LEN + w * 512 + c * 32 + g * 8);
            acc[tt] = __builtin_amdgcn_mfma_f32_16x16x32_bf16(pa, vb, acc[tt], 0, 0, 0);
        }
    }

    // ---- epilogue: 4-wave partial-O combine; wave w finalizes dh-tile w ----
    // Slot swizzle (tt^lane)&3 spreads the stride-64B pattern across 4 bank sets.
#pragma unroll
    for (int tt = 0; tt < 4; ++tt)
        *(f4v*)(Ocmb + w * 1024 + lane * 16 + ((tt ^ lane) & 3) * 4) = acc[tt];
    __syncthreads();
    f4v o = (f4v){0.f, 0.f, 0.f, 0.f};
#pragma unroll
    for (int w2 = 0; w2 < 4; ++w2) {
        const f4v p = *(const f4v*)(Ocmb + w2 * 1024 + lane * 16 + ((w ^ lane) & 3) * 4);
#pragma unroll
        for (int r = 0; r < 4; ++r) o[r] += p[r];
    }
    const int b_ = bh >> 4, h = bh & 15;
#pragma unroll
    for (int r = 0; r < 4; ++r) {
        out[((size_t)b_ * S_LEN + qt * 16 + g * 4 + r) * D_MODEL + h * HEAD_D + w * 16 + fr] = o[r];
    }
}

// ---------------- launch ----------------
extern "C" void kernel_launch(void* const* d_in, const int* in_sizes, int n_in,
                              void* d_out, int out_size, void* d_ws, size_t ws_size,
                              hipStream_t stream) {
    const float* x  = (const float*)d_in[0];
    const float* Wq = (const float*)d_in[1];
    const float* bq = (const float*)d_in[2];
    const float* Wk = (const float*)d_in[3];
    const float* bk = (const float*)d_in[4];
    const float* Wv = (const float*)d_in[5];
    const float* bv = (const float*)d_in[6];

    float* out = (float*)d_out;                              // [2,2048,1024]
    float* wts = out + (size_t)BATCH * S_LEN * D_MODEL;      // [2,16,2048,2048]

    unsigned short* xb    = (unsigned short*)d_ws;
    unsigned short* wqb   = xb  + (size_t)M_TOT * D_MODEL;
    unsigned short* wkb   = wqb + (size_t)D_MODEL * D_MODEL;
    unsigned short* wvb   = wkb + (size_t)D_MODEL * D_MODEL;
    unsigned short* q_ws  = wvb + (size_t)D_MODEL * D_MODEL;             // [b,h,s,dh]
    unsigned short* k_ws  = q_ws + (size_t)M_TOT * D_MODEL;              // [b,h,s,dh]
    unsigned short* vt_ws = k_ws + (size_t)M_TOT * D_MODEL;              // [b,h,dh,s]

    cvt_bf16<<<1024, 256, 0, stream>>>(x,  xb,  M_TOT * D_MODEL);
    cvt_bf16<<<256,  256, 0, stream>>>(Wq, wqb, D_MODEL * D_MODEL);
    cvt_bf16<<<256,  256, 0, stream>>>(Wk, wkb, D_MODEL * D_MODEL);
    cvt_bf16<<<256,  256, 0, stream>>>(Wv, wvb, D_MODEL * D_MODEL);

    qkv_gemm<<<dim3(32, 8, 3), 256, 0, stream>>>(xb, wqb, wkb, wvb, bq, bk, bv,
                                                 q_ws, k_ws, vt_ws);

    attn_fused3<<<BATCH * N_HEADS * (S_LEN / 16), 256, 0, stream>>>(q_ws, k_ws, vt_ws, out, wts);
}

// Round 6
// 239.616 us; speedup vs baseline: 1.9472x; 1.8442x over previous
//
#include <hip/hip_runtime.h>
#include <stdint.h>

// Problem constants
#define S_LEN   2048
#define D_MODEL 1024
#define N_HEADS 16
#define HEAD_D  64
#define BATCH   2
#define M_TOT   (BATCH * S_LEN)   // 4096 rows for the QKV projection GEMM

typedef __attribute__((ext_vector_type(8))) short s8v;            // 8 x bf16 (MFMA A/B frag)
typedef __attribute__((ext_vector_type(4))) float f4v;            // 4 x f32  (MFMA C/D frag)
typedef __attribute__((ext_vector_type(4))) unsigned short u4v;   // 4 x bf16 packed

__device__ __forceinline__ float bf2f(unsigned short u) {
    union { unsigned int i; float f; } c; c.i = ((unsigned int)u) << 16; return c.f;
}
__device__ __forceinline__ unsigned short f2bf(float f) {
    union { float f; unsigned int i; } c; c.f = f;
    unsigned int u = c.i + 0x7FFFu + ((c.i >> 16) & 1u);   // round-nearest-even
    return (unsigned short)(u >> 16);
}
__device__ __forceinline__ unsigned int pk2bf(float lo, float hi) {
    return (unsigned int)f2bf(lo) | ((unsigned int)f2bf(hi) << 16);
}
// exp2 via the HW transcendental (v_exp_f32)
__device__ __forceinline__ float hw_exp2(float x) { return __builtin_amdgcn_exp2f(x); }

// async global->LDS, 16B per lane; LDS dest is wave-uniform base (+lane*16 implicit)
#define GLD16(gp, lp) __builtin_amdgcn_global_load_lds(                      \
    (const __attribute__((address_space(1))) void*)(const void*)(gp),        \
    (__attribute__((address_space(3))) void*)(void*)(lp), 16, 0, 0)

// barrier WITHOUT draining vmcnt (prefetches stay in flight) but WITH lgkmcnt
// drain: no wave may signal the barrier while its ds_reads of the buffer that
// the next iteration's DMA will overwrite are still outstanding (R5 race fix).
#define BAR_LGKM() asm volatile("s_waitcnt lgkmcnt(0)\n\ts_barrier" ::: "memory")

// exp(x*0.125) == exp2(x * 0.125*log2(e))
#define EXP_SCALE 0.1803368801111204f

// ---------------- kernel 0: fp32 -> bf16 conversion ----------------
__global__ __launch_bounds__(256) void cvt_bf16(const float* __restrict__ src,
                                                unsigned short* __restrict__ dst, int n) {
    int i = (blockIdx.x * 256 + threadIdx.x) * 4;
    int stride = gridDim.x * 1024;
    for (; i < n; i += stride) {
        float4 v = *(const float4*)(src + i);
        u4v o;
        o[0] = f2bf(v.x); o[1] = f2bf(v.y); o[2] = f2bf(v.z); o[3] = f2bf(v.w);
        *(u4v*)(dst + i) = o;
    }
}

// ---------------- kernel 1: QKV projection GEMM (m97 structure) ----------------
__global__ __launch_bounds__(256) void qkv_gemm(
    const unsigned short* __restrict__ X,
    const unsigned short* __restrict__ Wq, const unsigned short* __restrict__ Wk,
    const unsigned short* __restrict__ Wv,
    const float* __restrict__ bq, const float* __restrict__ bk, const float* __restrict__ bv,
    unsigned short* __restrict__ q_ws, unsigned short* __restrict__ k_ws,
    unsigned short* __restrict__ vt_ws) {
    __shared__ unsigned short sA[128 * 32];
    __shared__ unsigned short sB[128 * 32];

    const int z = blockIdx.z;
    const unsigned short* Wm = (z == 0) ? Wq : ((z == 1) ? Wk : Wv);
    const float* bm = (z == 0) ? bq : ((z == 1) ? bk : bv);
    const int m0 = blockIdx.x * 128, n0 = blockIdx.y * 128;
    const int t = threadIdx.x;
    const int lane = t & 63, w = t >> 6;
    const int fr = lane & 15, g = lane >> 4;
    const int wr = w >> 1, wc = w & 1;

    f4v acc[4][4];
#pragma unroll
    for (int i = 0; i < 4; ++i)
#pragma unroll
        for (int j = 0; j < 4; ++j) acc[i][j] = (f4v){0.f, 0.f, 0.f, 0.f};

    const int rowL = t >> 2;
    const int colL = (t & 3) * 8;
    const unsigned short* gA = X + (size_t)(m0 + rowL) * D_MODEL + colL;
    const unsigned short* gB = Wm + (size_t)(n0 + rowL) * D_MODEL + colL;

    for (int kb = 0; kb < 32; ++kb) {
        const int k0 = kb * 32;
        GLD16(gA + k0,                 sA + w * 512);
        GLD16(gA + 64 * D_MODEL + k0,  sA + 2048 + w * 512);
        GLD16(gB + k0,                 sB + w * 512);
        GLD16(gB + 64 * D_MODEL + k0,  sB + 2048 + w * 512);
        __syncthreads();

        s8v af[4], bfv[4];
#pragma unroll
        for (int i = 0; i < 4; ++i)
            af[i] = *(const s8v*)(sA + (wr * 64 + i * 16 + fr) * 32 + g * 8);
#pragma unroll
        for (int j = 0; j < 4; ++j)
            bfv[j] = *(const s8v*)(sB + (wc * 64 + j * 16 + fr) * 32 + g * 8);
#pragma unroll
        for (int i = 0; i < 4; ++i)
#pragma unroll
            for (int j = 0; j < 4; ++j)
                acc[i][j] = __builtin_amdgcn_mfma_f32_16x16x32_bf16(af[i], bfv[j], acc[i][j], 0, 0, 0);
        __syncthreads();
    }

    const int e_base = n0 + wc * 64;
    const int m_base = m0 + wr * 64;
    if (z < 2) {
        unsigned short* dst = (z == 0) ? q_ws : k_ws;
#pragma unroll
        for (int i = 0; i < 4; ++i) {
#pragma unroll
            for (int j = 0; j < 4; ++j) {
                const int e = e_base + j * 16 + fr;
                const int h = e >> 6, dh = e & 63;
                const float bias = bm[e];
                const int mr = m_base + i * 16 + g * 4;
                const int b_ = mr >> 11, srow = mr & 2047;
                const size_t base = (((size_t)(b_ * N_HEADS + h) * S_LEN + srow) << 6) + dh;
#pragma unroll
                for (int r = 0; r < 4; ++r)
                    dst[base + ((size_t)r << 6)] = f2bf(acc[i][j][r] + bias);
            }
        }
    } else {
#pragma unroll
        for (int i = 0; i < 4; ++i) {
#pragma unroll
            for (int j = 0; j < 4; ++j) {
                const int e = e_base + j * 16 + fr;
                const int h = e >> 6, dh = e & 63;
                const float bias = bm[e];
                const int mr = m_base + i * 16 + g * 4;
                const int b_ = mr >> 11, srow = mr & 2047;
                u4v pk;
#pragma unroll
                for (int r = 0; r < 4; ++r) pk[r] = f2bf(acc[i][j][r] + bias);
                *(u4v*)(vt_ws + ((size_t)(b_ * N_HEADS + h) * HEAD_D + dh) * S_LEN + srow) = pk;
            }
        }
    }
}

// ---------------- kernel 2: fused attention, LDS-staged K/V ----------------
// WG (4 waves) = 64 q-rows of one (b,h); wave w owns q-rows [w*16, w*16+16) x ALL
// keys (rowsum is wave-local: 2 shfl_xor). K / V^T staged per-WG into LDS in
// 64-key chunks (8KB) via global_load_lds, double-buffered with counted vmcnt
// (never 0 mid-loop). Barriers: raw s_barrier preceded by lgkmcnt(0) drain
// (R5 race fix) — vmcnt prefetches stay in flight across them. LDS tiles are
// XOR-swizzled (block ^= row&7, 16B blocks in 128B rows) by pre-swizzling the
// GLOBAL source address (gld_lds dest must stay linear): fragment ds_read_b128
// are ~2-way conflict-free. Weights stored cooperatively from the P-exchange
// LDS tile: 4 rows x 256B contiguous segments per store instruction.
// Grid = 1024 WGs (exactly 4/CU, 40KB LDS). XCD-chunked block mapping.
__global__ __launch_bounds__(256, 4) void attn_fused4(
    const unsigned short* __restrict__ q_ws, const unsigned short* __restrict__ k_ws,
    const unsigned short* __restrict__ vt_ws,
    float* __restrict__ out, float* __restrict__ wts) {
    __shared__ unsigned short KL[2][4096];   // 2 x [64 keys][64 dh] bf16, swizzled
    __shared__ unsigned short VL[2][4096];   // 2 x [64 dh][64 keys] bf16, swizzled
    __shared__ unsigned short PLb[4][1024];  // per-wave [16 q][64 keys] bf16, swizzled

    const int t = threadIdx.x, lane = t & 63, w = t >> 6;
    const int fr = lane & 15, g = lane >> 4;
    const int blk = blockIdx.x;
    // bits [2:0]=xcd, [7:3]=qt, [9:8]=bh-within-xcd  ->  bijective, XCD-chunked
    const int bh = (blk & 7) * 4 + (blk >> 8);
    const int qt = (blk >> 3) & 31;

    const unsigned short* Qp = q_ws + ((size_t)bh * S_LEN + qt * 64 + w * 16) * HEAD_D;
    const unsigned short* Kp = k_ws + (size_t)bh * S_LEN * HEAD_D;
    const unsigned short* Vt = vt_ws + (size_t)bh * HEAD_D * S_LEN;

    // Q B-frag for swapped QK^T: lane(fr,g) = Q[q=fr][dh g*8..+7], [+32]
    const s8v qa0 = *(const s8v*)(Qp + fr * HEAD_D + g * 8);
    const s8v qa1 = *(const s8v*)(Qp + fr * HEAD_D + 32 + g * 8);

    // staging: thread t covers dest bytes t*16 (+4096); dest block cb holds
    // global block cb^(row&7)  (inverse-swizzled source, linear dest)
    auto stageK = [&](int c, int buf) {
#pragma unroll
        for (int j = 0; j < 2; ++j) {
            const int d = t * 16 + j * 4096;
            const int row = d >> 7, cb = (d >> 4) & 7;
            GLD16(Kp + (size_t)(c * 64 + row) * HEAD_D + ((cb ^ (row & 7)) << 3),
                  &KL[buf][w * 512 + j * 2048]);
        }
    };
    auto stageV = [&](int c, int buf) {
#pragma unroll
        for (int j = 0; j < 2; ++j) {
            const int d = t * 16 + j * 4096;
            const int row = d >> 7, cb = (d >> 4) & 7;
            GLD16(Vt + (size_t)row * S_LEN + c * 64 + ((cb ^ (row & 7)) << 3),
                  &VL[buf][w * 512 + j * 2048]);
        }
    };
    // swapped QK^T for one 16-key subtile: S[key st*16 + g*4+r][q=fr]
    auto qk16 = [&](const unsigned short* kb, int st) -> f4v {
        const int row = st * 16 + fr, m = row & 7;
        const s8v ka0 = *(const s8v*)((const char*)kb + row * 128 + ((g ^ m) << 4));
        const s8v ka1 = *(const s8v*)((const char*)kb + row * 128 + (((4 + g) ^ m) << 4));
        f4v s = (f4v){0.f, 0.f, 0.f, 0.f};
        s = __builtin_amdgcn_mfma_f32_16x16x32_bf16(ka0, qa0, s, 0, 0, 0);
        s = __builtin_amdgcn_mfma_f32_16x16x32_bf16(ka1, qa1, s, 0, 0, 0);
        return s;
    };

    // ---- pass A: rowsums (K staged, dbuf, counted vmcnt) ----
    float rsum = 0.f;
    stageK(0, 0);
    for (int c = 0; c < 32; ++c) {
        const int cur = c & 1;
        if (c < 31) stageK(c + 1, cur ^ 1);
        if (c < 31) asm volatile("s_waitcnt vmcnt(2)" ::: "memory");
        else        asm volatile("s_waitcnt vmcnt(0)" ::: "memory");
        asm volatile("s_barrier" ::: "memory");
        const unsigned short* kb = KL[cur];
#pragma unroll
        for (int st = 0; st < 4; ++st) {
            const f4v s = qk16(kb, st);
#pragma unroll
            for (int r = 0; r < 4; ++r) rsum += hw_exp2(s[r] * EXP_SCALE);
        }
        BAR_LGKM();   // reads of KL[cur] complete in ALL waves before overwrite
    }
    rsum += __shfl_xor(rsum, 16);
    rsum += __shfl_xor(rsum, 32);
    const float inv = 1.f / rsum;            // per-lane: inv rowsum of q-row fr

    // ---- pass B: recompute scores, store normalized weights, PV ----
    f4v acc[4];
#pragma unroll
    for (int i = 0; i < 4; ++i) acc[i] = (f4v){0.f, 0.f, 0.f, 0.f};
    unsigned short* PL = PLb[w];
    const int swp = (fr & 7) << 4;
    float* wbase = wts + ((size_t)bh * S_LEN + qt * 64 + w * 16) * S_LEN;

    stageK(0, 0); stageV(0, 0);
    for (int c = 0; c < 32; ++c) {
        const int cur = c & 1;
        if (c < 31) { stageK(c + 1, cur ^ 1); stageV(c + 1, cur ^ 1); }
        // vmcnt budget: queue = [cur-buf 4 loads][prev-iter 4 stores][next-buf
        // 4 loads]; counted waits drain only the cur-buf loads.
        if (c == 0)      asm volatile("s_waitcnt vmcnt(4)" ::: "memory");
        else if (c < 31) asm volatile("s_waitcnt vmcnt(8)" ::: "memory");
        else             asm volatile("s_waitcnt vmcnt(4)" ::: "memory");
        asm volatile("s_barrier" ::: "memory");

        const unsigned short* kb = KL[cur];
#pragma unroll
        for (int st = 0; st < 4; ++st) {
            const f4v s = qk16(kb, st);
            f4v p;
#pragma unroll
            for (int r = 0; r < 4; ++r) p[r] = hw_exp2(s[r] * EXP_SCALE) * inv;
            // exchange normalized bf16 P into PL: row q=fr, keys st*16+g*4..+3
            const int base = fr * 128 + st * 32 + g * 8;
            *(unsigned int*)((char*)PL + ((base)     ^ swp)) = pk2bf(p[0], p[1]);
            *(unsigned int*)((char*)PL + ((base + 4) ^ swp)) = pk2bf(p[2], p[3]);
        }

        // cooperative weight store: 4 rows x (16 lanes x 16B = 256B) per instr
        {
            const int r0 = lane >> 4, cc = lane & 15;
#pragma unroll
            for (int i = 0; i < 4; ++i) {
                const int row = i * 4 + r0;
                const u4v pw = *(const u4v*)((const char*)PL +
                                             ((row * 128 + cc * 8) ^ ((row & 7) << 4)));
                f4v o;
#pragma unroll
                for (int e = 0; e < 4; ++e) o[e] = bf2f(pw[e]);
                *(f4v*)(wbase + (size_t)row * S_LEN + c * 64 + cc * 4) = o;
            }
        }

        // PV: acc[tt] += P[16q x 32k] @ V[32k x 16dh]
        const char* vl = (const char*)VL[cur];
#pragma unroll
        for (int ks = 0; ks < 2; ++ks) {
            const s8v pa = *(const s8v*)((const char*)PL +
                                         ((fr * 128 + ks * 64 + g * 16) ^ swp));
#pragma unroll
            for (int tt = 0; tt < 4; ++tt) {
                const int vrow = tt * 16 + fr;
                const s8v vv = *(const s8v*)(vl + vrow * 128 +
                                             (((ks * 4 + g) ^ (vrow & 7)) << 4));
                acc[tt] = __builtin_amdgcn_mfma_f32_16x16x32_bf16(pa, vv, acc[tt], 0, 0, 0);
            }
        }
        BAR_LGKM();   // reads of KL/VL[cur] complete in ALL waves before overwrite
    }

    // ---- epilogue: O (already normalized) ----
    const int b_ = bh >> 4, h = bh & 15;
#pragma unroll
    for (int tt = 0; tt < 4; ++tt)
#pragma unroll
        for (int r = 0; r < 4; ++r)
            out[((size_t)b_ * S_LEN + qt * 64 + w * 16 + g * 4 + r) * D_MODEL +
                h * HEAD_D + tt * 16 + fr] = acc[tt][r];
}

// ---------------- launch ----------------
extern "C" void kernel_launch(void* const* d_in, const int* in_sizes, int n_in,
                              void* d_out, int out_size, void* d_ws, size_t ws_size,
                              hipStream_t stream) {
    const float* x  = (const float*)d_in[0];
    const float* Wq = (const float*)d_in[1];
    const float* bq = (const float*)d_in[2];
    const float* Wk = (const float*)d_in[3];
    const float* bk = (const float*)d_in[4];
    const float* Wv = (const float*)d_in[5];
    const float* bv = (const float*)d_in[6];

    float* out = (float*)d_out;                              // [2,2048,1024]
    float* wts = out + (size_t)BATCH * S_LEN * D_MODEL;      // [2,16,2048,2048]

    unsigned short* xb    = (unsigned short*)d_ws;
    unsigned short* wqb   = xb  + (size_t)M_TOT * D_MODEL;
    unsigned short* wkb   = wqb + (size_t)D_MODEL * D_MODEL;
    unsigned short* wvb   = wkb + (size_t)D_MODEL * D_MODEL;
    unsigned short* q_ws  = wvb + (size_t)D_MODEL * D_MODEL;             // [b,h,s,dh]
    unsigned short* k_ws  = q_ws + (size_t)M_TOT * D_MODEL;              // [b,h,s,dh]
    unsigned short* vt_ws = k_ws + (size_t)M_TOT * D_MODEL;              // [b,h,dh,s]

    cvt_bf16<<<1024, 256, 0, stream>>>(x,  xb,  M_TOT * D_MODEL);
    cvt_bf16<<<256,  256, 0, stream>>>(Wq, wqb, D_MODEL * D_MODEL);
    cvt_bf16<<<256,  256, 0, stream>>>(Wk, wkb, D_MODEL * D_MODEL);
    cvt_bf16<<<256,  256, 0, stream>>>(Wv, wvb, D_MODEL * D_MODEL);

    qkv_gemm<<<dim3(32, 8, 3), 256, 0, stream>>>(xb, wqb, wkb, wvb, bq, bk, bv,
                                                 q_ws, k_ws, vt_ws);

    attn_fused4<<<BATCH * N_HEADS * (S_LEN / 64), 256, 0, stream>>>(q_ws, k_ws, vt_ws, out, wts);
}

// Round 7
// 207.101 us; speedup vs baseline: 2.2529x; 1.1570x over previous
//
#include <hip/hip_runtime.h>
#include <stdint.h>

// Problem constants
#define S_LEN   2048
#define D_MODEL 1024
#define N_HEADS 16
#define HEAD_D  64
#define BATCH   2
#define M_TOT   (BATCH * S_LEN)   // 4096 rows for the QKV projection GEMM

typedef __attribute__((ext_vector_type(8))) short s8v;            // 8 x bf16 (MFMA A/B frag)
typedef __attribute__((ext_vector_type(4))) float f4v;            // 4 x f32  (MFMA C/D frag)
typedef __attribute__((ext_vector_type(4))) unsigned short u4v;   // 4 x bf16 packed

__device__ __forceinline__ float bf2f(unsigned short u) {
    union { unsigned int i; float f; } c; c.i = ((unsigned int)u) << 16; return c.f;
}
__device__ __forceinline__ unsigned short f2bf(float f) {
    union { float f; unsigned int i; } c; c.f = f;
    unsigned int u = c.i + 0x7FFFu + ((c.i >> 16) & 1u);   // round-nearest-even
    return (unsigned short)(u >> 16);
}
__device__ __forceinline__ unsigned int pk2bf(float lo, float hi) {
    return (unsigned int)f2bf(lo) | ((unsigned int)f2bf(hi) << 16);
}
// exp2 via the HW transcendental (v_exp_f32)
__device__ __forceinline__ float hw_exp2(float x) { return __builtin_amdgcn_exp2f(x); }

// async global->LDS, 16B per lane; LDS dest is wave-uniform base (+lane*16 implicit)
#define GLD16(gp, lp) __builtin_amdgcn_global_load_lds(                      \
    (const __attribute__((address_space(1))) void*)(const void*)(gp),        \
    (__attribute__((address_space(3))) void*)(void*)(lp), 16, 0, 0)

// barrier WITHOUT draining vmcnt (prefetches stay in flight) but WITH lgkmcnt
// drain: no wave may signal the barrier while its ds_reads of the buffer that
// the next iteration's DMA will overwrite are still outstanding (R5 race fix).
#define BAR_LGKM() asm volatile("s_waitcnt lgkmcnt(0)\n\ts_barrier" ::: "memory")

// exp(x*0.125) == exp2(x * 0.125*log2(e))
#define EXP_SCALE 0.1803368801111204f

// ---------------- kernel 0: fp32 -> bf16 conversion ----------------
__global__ __launch_bounds__(256) void cvt_bf16(const float* __restrict__ src,
                                                unsigned short* __restrict__ dst, int n) {
    int i = (blockIdx.x * 256 + threadIdx.x) * 4;
    int stride = gridDim.x * 1024;
    for (; i < n; i += stride) {
        float4 v = *(const float4*)(src + i);
        u4v o;
        o[0] = f2bf(v.x); o[1] = f2bf(v.y); o[2] = f2bf(v.z); o[3] = f2bf(v.w);
        *(u4v*)(dst + i) = o;
    }
}

// ---------------- kernel 1: QKV projection GEMM (m97 structure) ----------------
__global__ __launch_bounds__(256) void qkv_gemm(
    const unsigned short* __restrict__ X,
    const unsigned short* __restrict__ Wq, const unsigned short* __restrict__ Wk,
    const unsigned short* __restrict__ Wv,
    const float* __restrict__ bq, const float* __restrict__ bk, const float* __restrict__ bv,
    unsigned short* __restrict__ q_ws, unsigned short* __restrict__ k_ws,
    unsigned short* __restrict__ vt_ws) {
    __shared__ unsigned short sA[128 * 32];
    __shared__ unsigned short sB[128 * 32];

    const int z = blockIdx.z;
    const unsigned short* Wm = (z == 0) ? Wq : ((z == 1) ? Wk : Wv);
    const float* bm = (z == 0) ? bq : ((z == 1) ? bk : bv);
    const int m0 = blockIdx.x * 128, n0 = blockIdx.y * 128;
    const int t = threadIdx.x;
    const int lane = t & 63, w = t >> 6;
    const int fr = lane & 15, g = lane >> 4;
    const int wr = w >> 1, wc = w & 1;

    f4v acc[4][4];
#pragma unroll
    for (int i = 0; i < 4; ++i)
#pragma unroll
        for (int j = 0; j < 4; ++j) acc[i][j] = (f4v){0.f, 0.f, 0.f, 0.f};

    const int rowL = t >> 2;
    const int colL = (t & 3) * 8;
    const unsigned short* gA = X + (size_t)(m0 + rowL) * D_MODEL + colL;
    const unsigned short* gB = Wm + (size_t)(n0 + rowL) * D_MODEL + colL;

    for (int kb = 0; kb < 32; ++kb) {
        const int k0 = kb * 32;
        GLD16(gA + k0,                 sA + w * 512);
        GLD16(gA + 64 * D_MODEL + k0,  sA + 2048 + w * 512);
        GLD16(gB + k0,                 sB + w * 512);
        GLD16(gB + 64 * D_MODEL + k0,  sB + 2048 + w * 512);
        __syncthreads();

        s8v af[4], bfv[4];
#pragma unroll
        for (int i = 0; i < 4; ++i)
            af[i] = *(const s8v*)(sA + (wr * 64 + i * 16 + fr) * 32 + g * 8);
#pragma unroll
        for (int j = 0; j < 4; ++j)
            bfv[j] = *(const s8v*)(sB + (wc * 64 + j * 16 + fr) * 32 + g * 8);
#pragma unroll
        for (int i = 0; i < 4; ++i)
#pragma unroll
            for (int j = 0; j < 4; ++j)
                acc[i][j] = __builtin_amdgcn_mfma_f32_16x16x32_bf16(af[i], bfv[j], acc[i][j], 0, 0, 0);
        __syncthreads();
    }

    const int e_base = n0 + wc * 64;
    const int m_base = m0 + wr * 64;
    if (z < 2) {
        unsigned short* dst = (z == 0) ? q_ws : k_ws;
#pragma unroll
        for (int i = 0; i < 4; ++i) {
#pragma unroll
            for (int j = 0; j < 4; ++j) {
                const int e = e_base + j * 16 + fr;
                const int h = e >> 6, dh = e & 63;
                const float bias = bm[e];
                const int mr = m_base + i * 16 + g * 4;
                const int b_ = mr >> 11, srow = mr & 2047;
                const size_t base = (((size_t)(b_ * N_HEADS + h) * S_LEN + srow) << 6) + dh;
#pragma unroll
                for (int r = 0; r < 4; ++r)
                    dst[base + ((size_t)r << 6)] = f2bf(acc[i][j][r] + bias);
            }
        }
    } else {
#pragma unroll
        for (int i = 0; i < 4; ++i) {
#pragma unroll
            for (int j = 0; j < 4; ++j) {
                const int e = e_base + j * 16 + fr;
                const int h = e >> 6, dh = e & 63;
                const float bias = bm[e];
                const int mr = m_base + i * 16 + g * 4;
                const int b_ = mr >> 11, srow = mr & 2047;
                u4v pk;
#pragma unroll
                for (int r = 0; r < 4; ++r) pk[r] = f2bf(acc[i][j][r] + bias);
                *(u4v*)(vt_ws + ((size_t)(b_ * N_HEADS + h) * HEAD_D + dh) * S_LEN + srow) = pk;
            }
        }
    }
}

// ---------------- kernel 2: fused attention, LDS-staged K/V ----------------
// WG (4 waves) = 64 q-rows of one (b,h); wave w owns q-rows [w*16, w*16+16) x ALL
// keys (rowsum is wave-local: 2 shfl_xor). K / V^T staged per-WG into LDS in
// 64-key chunks (8KB) via global_load_lds, double-buffered with counted vmcnt
// (never 0 mid-loop). Barriers: raw s_barrier preceded by lgkmcnt(0) drain
// (R5 race fix) — vmcnt prefetches stay in flight across them. LDS tiles are
// XOR-swizzled (block ^= row&7, 16B blocks in 128B rows) by pre-swizzling the
// GLOBAL source address (gld_lds dest must stay linear): fragment ds_read_b128
// are ~2-way conflict-free. Weights stored cooperatively from the P-exchange
// LDS tile: 4 rows x 256B contiguous segments per store instruction.
// R7: weight/out stores are NONTEMPORAL (streaming, never re-read) so 540MB of
// writes stop thrashing the 4MB/XCD L2 that holds K/V/Q (R4: FETCH 95MB vs
// ~24MB ideal). Grid = 1024 WGs (4/CU, 40KB LDS). XCD-chunked block mapping.
__global__ __launch_bounds__(256, 4) void attn_fused4(
    const unsigned short* __restrict__ q_ws, const unsigned short* __restrict__ k_ws,
    const unsigned short* __restrict__ vt_ws,
    float* __restrict__ out, float* __restrict__ wts) {
    __shared__ unsigned short KL[2][4096];   // 2 x [64 keys][64 dh] bf16, swizzled
    __shared__ unsigned short VL[2][4096];   // 2 x [64 dh][64 keys] bf16, swizzled
    __shared__ unsigned short PLb[4][1024];  // per-wave [16 q][64 keys] bf16, swizzled

    const int t = threadIdx.x, lane = t & 63, w = t >> 6;
    const int fr = lane & 15, g = lane >> 4;
    const int blk = blockIdx.x;
    // bits [2:0]=xcd, [7:3]=qt, [9:8]=bh-within-xcd  ->  bijective, XCD-chunked
    const int bh = (blk & 7) * 4 + (blk >> 8);
    const int qt = (blk >> 3) & 31;

    const unsigned short* Qp = q_ws + ((size_t)bh * S_LEN + qt * 64 + w * 16) * HEAD_D;
    const unsigned short* Kp = k_ws + (size_t)bh * S_LEN * HEAD_D;
    const unsigned short* Vt = vt_ws + (size_t)bh * HEAD_D * S_LEN;

    // Q B-frag for swapped QK^T: lane(fr,g) = Q[q=fr][dh g*8..+7], [+32]
    const s8v qa0 = *(const s8v*)(Qp + fr * HEAD_D + g * 8);
    const s8v qa1 = *(const s8v*)(Qp + fr * HEAD_D + 32 + g * 8);

    // staging: thread t covers dest bytes t*16 (+4096); dest block cb holds
    // global block cb^(row&7)  (inverse-swizzled source, linear dest)
    auto stageK = [&](int c, int buf) {
#pragma unroll
        for (int j = 0; j < 2; ++j) {
            const int d = t * 16 + j * 4096;
            const int row = d >> 7, cb = (d >> 4) & 7;
            GLD16(Kp + (size_t)(c * 64 + row) * HEAD_D + ((cb ^ (row & 7)) << 3),
                  &KL[buf][w * 512 + j * 2048]);
        }
    };
    auto stageV = [&](int c, int buf) {
#pragma unroll
        for (int j = 0; j < 2; ++j) {
            const int d = t * 16 + j * 4096;
            const int row = d >> 7, cb = (d >> 4) & 7;
            GLD16(Vt + (size_t)row * S_LEN + c * 64 + ((cb ^ (row & 7)) << 3),
                  &VL[buf][w * 512 + j * 2048]);
        }
    };
    // swapped QK^T for one 16-key subtile: S[key st*16 + g*4+r][q=fr]
    auto qk16 = [&](const unsigned short* kb, int st) -> f4v {
        const int row = st * 16 + fr, m = row & 7;
        const s8v ka0 = *(const s8v*)((const char*)kb + row * 128 + ((g ^ m) << 4));
        const s8v ka1 = *(const s8v*)((const char*)kb + row * 128 + (((4 + g) ^ m) << 4));
        f4v s = (f4v){0.f, 0.f, 0.f, 0.f};
        s = __builtin_amdgcn_mfma_f32_16x16x32_bf16(ka0, qa0, s, 0, 0, 0);
        s = __builtin_amdgcn_mfma_f32_16x16x32_bf16(ka1, qa1, s, 0, 0, 0);
        return s;
    };

    // ---- pass A: rowsums (K staged, dbuf, counted vmcnt) ----
    float rsum = 0.f;
    stageK(0, 0);
    for (int c = 0; c < 32; ++c) {
        const int cur = c & 1;
        if (c < 31) stageK(c + 1, cur ^ 1);
        if (c < 31) asm volatile("s_waitcnt vmcnt(2)" ::: "memory");
        else        asm volatile("s_waitcnt vmcnt(0)" ::: "memory");
        asm volatile("s_barrier" ::: "memory");
        const unsigned short* kb = KL[cur];
#pragma unroll
        for (int st = 0; st < 4; ++st) {
            const f4v s = qk16(kb, st);
#pragma unroll
            for (int r = 0; r < 4; ++r) rsum += hw_exp2(s[r] * EXP_SCALE);
        }
        BAR_LGKM();   // reads of KL[cur] complete in ALL waves before overwrite
    }
    rsum += __shfl_xor(rsum, 16);
    rsum += __shfl_xor(rsum, 32);
    const float inv = 1.f / rsum;            // per-lane: inv rowsum of q-row fr

    // ---- pass B: recompute scores, store normalized weights, PV ----
    f4v acc[4];
#pragma unroll
    for (int i = 0; i < 4; ++i) acc[i] = (f4v){0.f, 0.f, 0.f, 0.f};
    unsigned short* PL = PLb[w];
    const int swp = (fr & 7) << 4;
    float* wbase = wts + ((size_t)bh * S_LEN + qt * 64 + w * 16) * S_LEN;

    stageK(0, 0); stageV(0, 0);
    for (int c = 0; c < 32; ++c) {
        const int cur = c & 1;
        if (c < 31) { stageK(c + 1, cur ^ 1); stageV(c + 1, cur ^ 1); }
        // vmcnt budget: queue = [cur-buf 4 loads][prev-iter 4 stores][next-buf
        // 4 loads]; counted waits drain only the cur-buf loads.
        if (c == 0)      asm volatile("s_waitcnt vmcnt(4)" ::: "memory");
        else if (c < 31) asm volatile("s_waitcnt vmcnt(8)" ::: "memory");
        else             asm volatile("s_waitcnt vmcnt(4)" ::: "memory");
        asm volatile("s_barrier" ::: "memory");

        const unsigned short* kb = KL[cur];
#pragma unroll
        for (int st = 0; st < 4; ++st) {
            const f4v s = qk16(kb, st);
            f4v p;
#pragma unroll
            for (int r = 0; r < 4; ++r) p[r] = hw_exp2(s[r] * EXP_SCALE) * inv;
            // exchange normalized bf16 P into PL: row q=fr, keys st*16+g*4..+3
            const int base = fr * 128 + st * 32 + g * 8;
            *(unsigned int*)((char*)PL + ((base)     ^ swp)) = pk2bf(p[0], p[1]);
            *(unsigned int*)((char*)PL + ((base + 4) ^ swp)) = pk2bf(p[2], p[3]);
        }

        // cooperative weight store: 4 rows x (16 lanes x 16B = 256B) per instr,
        // NONTEMPORAL (streamed, never re-read — keep L2 for K/V/Q)
        {
            const int r0 = lane >> 4, cc = lane & 15;
#pragma unroll
            for (int i = 0; i < 4; ++i) {
                const int row = i * 4 + r0;
                const u4v pw = *(const u4v*)((const char*)PL +
                                             ((row * 128 + cc * 8) ^ ((row & 7) << 4)));
                f4v o;
#pragma unroll
                for (int e = 0; e < 4; ++e) o[e] = bf2f(pw[e]);
                __builtin_nontemporal_store(o,
                    (f4v*)(wbase + (size_t)row * S_LEN + c * 64 + cc * 4));
            }
        }

        // PV: acc[tt] += P[16q x 32k] @ V[32k x 16dh]
        const char* vl = (const char*)VL[cur];
#pragma unroll
        for (int ks = 0; ks < 2; ++ks) {
            const s8v pa = *(const s8v*)((const char*)PL +
                                         ((fr * 128 + ks * 64 + g * 16) ^ swp));
#pragma unroll
            for (int tt = 0; tt < 4; ++tt) {
                const int vrow = tt * 16 + fr;
                const s8v vv = *(const s8v*)(vl + vrow * 128 +
                                             (((ks * 4 + g) ^ (vrow & 7)) << 4));
                acc[tt] = __builtin_amdgcn_mfma_f32_16x16x32_bf16(pa, vv, acc[tt], 0, 0, 0);
            }
        }
        BAR_LGKM();   // reads of KL/VL[cur] complete in ALL waves before overwrite
    }

    // ---- epilogue: O (already normalized), nontemporal ----
    const int b_ = bh >> 4, h = bh & 15;
#pragma unroll
    for (int tt = 0; tt < 4; ++tt)
#pragma unroll
        for (int r = 0; r < 4; ++r)
            __builtin_nontemporal_store(acc[tt][r],
                &out[((size_t)b_ * S_LEN + qt * 64 + w * 16 + g * 4 + r) * D_MODEL +
                     h * HEAD_D + tt * 16 + fr]);
}

// ---------------- launch ----------------
extern "C" void kernel_launch(void* const* d_in, const int* in_sizes, int n_in,
                              void* d_out, int out_size, void* d_ws, size_t ws_size,
                              hipStream_t stream) {
    const float* x  = (const float*)d_in[0];
    const float* Wq = (const float*)d_in[1];
    const float* bq = (const float*)d_in[2];
    const float* Wk = (const float*)d_in[3];
    const float* bk = (const float*)d_in[4];
    const float* Wv = (const float*)d_in[5];
    const float* bv = (const float*)d_in[6];

    float* out = (float*)d_out;                              // [2,2048,1024]
    float* wts = out + (size_t)BATCH * S_LEN * D_MODEL;      // [2,16,2048,2048]

    unsigned short* xb    = (unsigned short*)d_ws;
    unsigned short* wqb   = xb  + (size_t)M_TOT * D_MODEL;
    unsigned short* wkb   = wqb + (size_t)D_MODEL * D_MODEL;
    unsigned short* wvb   = wkb + (size_t)D_MODEL * D_MODEL;
    unsigned short* q_ws  = wvb + (size_t)D_MODEL * D_MODEL;             // [b,h,s,dh]
    unsigned short* k_ws  = q_ws + (size_t)M_TOT * D_MODEL;              // [b,h,s,dh]
    unsigned short* vt_ws = k_ws + (size_t)M_TOT * D_MODEL;              // [b,h,dh,s]

    cvt_bf16<<<1024, 256, 0, stream>>>(x,  xb,  M_TOT * D_MODEL);
    cvt_bf16<<<256,  256, 0, stream>>>(Wq, wqb, D_MODEL * D_MODEL);
    cvt_bf16<<<256,  256, 0, stream>>>(Wk, wkb, D_MODEL * D_MODEL);
    cvt_bf16<<<256,  256, 0, stream>>>(Wv, wvb, D_MODEL * D_MODEL);

    qkv_gemm<<<dim3(32, 8, 3), 256, 0, stream>>>(xb, wqb, wkb, wvb, bq, bk, bv,
                                                 q_ws, k_ws, vt_ws);

    attn_fused4<<<BATCH * N_HEADS * (S_LEN / 64), 256, 0, stream>>>(q_ws, k_ws, vt_ws, out, wts);
}